// Round 1
// baseline (217.654 us; speedup 1.0000x reference)
//
#include <hip/hip_runtime.h>
#include <hip/hip_bf16.h>

typedef __bf16 bf16x8 __attribute__((ext_vector_type(8)));
typedef __bf16 bf16x4 __attribute__((ext_vector_type(4)));
typedef float  f32x4  __attribute__((ext_vector_type(4)));

// ---------------------------------------------------------------------------
// neigh_mask dtype detection: bool may arrive as uint8 bytes or int32 words.
// View as int32: if any word > 1, it must be packed uint8 bytes (e.g. a row
// with count>=2 gives 0x00000101). If all words are 0/1 it's int32 bools.
// flag (in d_ws): 1 = uint8 layout, 0 = int32 layout.
// ---------------------------------------------------------------------------
__global__ void init_flag_kernel(int* flag) { *flag = 0; }

__global__ void detect_mask_kernel(const unsigned* __restrict__ mw, int nwords,
                                   int* __restrict__ flag) {
    int any = 0;
    for (int i = blockIdx.x * blockDim.x + threadIdx.x; i < nwords;
         i += gridDim.x * blockDim.x)
        if (mw[i] > 1u) any = 1;
    if (__any(any)) {
        if ((threadIdx.x & 63) == 0) atomicOr(flag, 1);
    }
}

// ---------------------------------------------------------------------------
// Main kernel: 1 wave per node, 4 waves per block (256 thr), grid-stride.
// MFMA 16x16x32 bf16. Verified layouts (learn_hip m89):
//   A: row = lane&15, k = (lane>>4)*8 + i   (8 contiguous-k bf16 per lane)
//   B: col = lane&15, k = (lane>>4)*8 + i
//   C/D: col = lane&15, row = (lane>>4)*4 + reg
// ---------------------------------------------------------------------------
__global__ __launch_bounds__(256) void graphrec_agg_kernel(
    const float* __restrict__ u2e,
    const float* __restrict__ W1, const float* __restrict__ b1,
    const float* __restrict__ W2, const float* __restrict__ b2,
    const float* __restrict__ W3, const float* __restrict__ b3,
    const int* __restrict__ nodes, const int* __restrict__ neigh_idx,
    const void* __restrict__ mask, const int* __restrict__ flag,
    float* __restrict__ out, int N)
{
    // Block-shared weight fragments (B layout), built once per block.
    __shared__ __align__(16) __bf16 w1f[16][64][8];   // [kt*4+nt][lane][i] 16 KiB
    __shared__ __align__(16) __bf16 w2f[8][64][8];    // [kt*4+nt][lane][i]  8 KiB
    // Per-wave buffers.
    __shared__ __align__(16) float  eu[4][32][64];    // f32 e_u rows      32 KiB
    __shared__ __align__(16) __bf16 afrag[4][2][2][64][8]; // A frags      16 KiB
    __shared__ __align__(16) __bf16 urep[4][64];      // bf16 u_rep        0.5 KiB
    __shared__ float att_s[4][32];                    //                   0.5 KiB

    const int tid = threadIdx.x;
    const int w = tid >> 6;        // wave in block
    const int l = tid & 63;        // lane
    const int g = l >> 4;          // 16-lane group
    const int c = l & 15;          // lane within group

    // ---- stage W1 (128x64) and W2 (64x64) as bf16 B-fragments ----
    for (int f = w; f < 16; f += 4) {
        int kt = f >> 2, nt = f & 3;
        int r0 = kt * 32 + g * 8, col = nt * 16 + c;
        bf16x8 t;
        #pragma unroll
        for (int i = 0; i < 8; ++i) t[i] = (__bf16)W1[(r0 + i) * 64 + col];
        *(bf16x8*)&w1f[f][l][0] = t;
    }
    for (int f = w; f < 8; f += 4) {
        int kt = f >> 2, nt = f & 3;
        int r0 = kt * 32 + g * 8, col = nt * 16 + c;
        bf16x8 t;
        #pragma unroll
        for (int i = 0; i < 8; ++i) t[i] = (__bf16)W2[(r0 + i) * 64 + col];
        *(bf16x8*)&w2f[f][l][0] = t;
    }
    __syncthreads();

    // Per-lane bias / W3 caches (col = nt*16 + c matches C-frag col).
    float b1v[4], b2v[4], w3v[4];
    #pragma unroll
    for (int nt = 0; nt < 4; ++nt) {
        b1v[nt] = b1[nt * 16 + c];
        b2v[nt] = b2[nt * 16 + c];
        w3v[nt] = W3[nt * 16 + c];
    }
    const float b3s = b3[0];
    const int layout8 = *flag;
    const unsigned char* m8p  = (const unsigned char*)mask;
    const int*           m32p = (const int*)mask;

    for (int n = blockIdx.x * 4 + w; n < N; n += gridDim.x * 4) {
        // ---- neighbor indices (lanes 0..31) and mask ballot ----
        int vidx = 0;
        if (l < 32) vidx = neigh_idx[n * 32 + l];
        bool mv = false;
        if (l < 32) mv = layout8 ? (m8p[n * 32 + l] != 0)
                                 : (m32p[n * 32 + l] != 0);
        unsigned long long bal = __ballot(mv);

        // ---- center embedding u_rep ----
        int un = nodes[n];
        float ur = u2e[(size_t)un * 64 + l];
        urep[w][l] = (__bf16)ur;

        // ---- gather e_u: 4 rows per iteration via float4 ----
        #pragma unroll
        for (int kb = 0; kb < 8; ++kb) {
            int k = kb * 4 + g;
            int idx = __shfl(vidx, k);
            f32x4 v = *(const f32x4*)(u2e + (size_t)idx * 64 + c * 4);
            *(f32x4*)&eu[w][k][c * 4] = v;
            // bf16 copy into A-fragment layout
            int d0 = c * 4;
            bf16x4 bv;
            bv[0] = (__bf16)v[0]; bv[1] = (__bf16)v[1];
            bv[2] = (__bf16)v[2]; bv[3] = (__bf16)v[3];
            int lanep = (k & 15) + (((d0 & 31) >> 3) << 4);
            *(bf16x4*)&afrag[w][k >> 4][d0 >> 5][lanep][d0 & 7] = bv;
        }

        // ---- layer 1: h1 = relu([e_u | u_rep] @ W1 + b1), write A2 frags ----
        #pragma unroll
        for (int mt = 0; mt < 2; ++mt) {
            bf16x8 a0 = *(const bf16x8*)&afrag[w][mt][0][l][0];
            bf16x8 a1 = *(const bf16x8*)&afrag[w][mt][1][l][0];
            bf16x8 a2 = *(const bf16x8*)&urep[w][g * 8];
            bf16x8 a3 = *(const bf16x8*)&urep[w][32 + g * 8];
            #pragma unroll
            for (int nt = 0; nt < 4; ++nt) {
                f32x4 cc = {0.f, 0.f, 0.f, 0.f};
                cc = __builtin_amdgcn_mfma_f32_16x16x32_bf16(a0, *(const bf16x8*)&w1f[0 + nt][l][0], cc, 0, 0, 0);
                cc = __builtin_amdgcn_mfma_f32_16x16x32_bf16(a1, *(const bf16x8*)&w1f[4 + nt][l][0], cc, 0, 0, 0);
                cc = __builtin_amdgcn_mfma_f32_16x16x32_bf16(a2, *(const bf16x8*)&w1f[8 + nt][l][0], cc, 0, 0, 0);
                cc = __builtin_amdgcn_mfma_f32_16x16x32_bf16(a3, *(const bf16x8*)&w1f[12 + nt][l][0], cc, 0, 0, 0);
                #pragma unroll
                for (int r = 0; r < 4; ++r) {
                    float hv = fmaxf(cc[r] + b1v[nt], 0.f);
                    // dest: A2[row = mt*16+g*4+r][j = nt*16+c]
                    int lanep = g * 4 + r + ((((nt & 1) << 1) + (c >> 3)) << 4);
                    afrag[w][mt][nt >> 1][lanep][c & 7] = (__bf16)hv;
                }
            }
        }

        // ---- layer 2 + per-lane score partials ----
        float p[2][4];
        #pragma unroll
        for (int mt = 0; mt < 2; ++mt) {
            bf16x8 a0 = *(const bf16x8*)&afrag[w][mt][0][l][0];
            bf16x8 a1 = *(const bf16x8*)&afrag[w][mt][1][l][0];
            float pr0 = 0.f, pr1 = 0.f, pr2 = 0.f, pr3 = 0.f;
            #pragma unroll
            for (int nt = 0; nt < 4; ++nt) {
                f32x4 cc = {0.f, 0.f, 0.f, 0.f};
                cc = __builtin_amdgcn_mfma_f32_16x16x32_bf16(a0, *(const bf16x8*)&w2f[0 + nt][l][0], cc, 0, 0, 0);
                cc = __builtin_amdgcn_mfma_f32_16x16x32_bf16(a1, *(const bf16x8*)&w2f[4 + nt][l][0], cc, 0, 0, 0);
                pr0 += fmaxf(cc[0] + b2v[nt], 0.f) * w3v[nt];
                pr1 += fmaxf(cc[1] + b2v[nt], 0.f) * w3v[nt];
                pr2 += fmaxf(cc[2] + b2v[nt], 0.f) * w3v[nt];
                pr3 += fmaxf(cc[3] + b2v[nt], 0.f) * w3v[nt];
            }
            p[mt][0] = pr0; p[mt][1] = pr1; p[mt][2] = pr2; p[mt][3] = pr3;
        }

        // ---- reduce score partials over the 16 columns (lanes c=0..15) ----
        float s[8];
        #pragma unroll
        for (int m = 0; m < 8; ++m) {
            float v = p[m >> 2][m & 3];
            v += __shfl_xor(v, 1);
            v += __shfl_xor(v, 2);
            v += __shfl_xor(v, 4);
            v += __shfl_xor(v, 8);
            s[m] = v + b3s;
        }

        // ---- masked softmax over k=0..31 (rows distributed: k=mt*16+g*4+r) ----
        bool vald[8];
        float m8 = -1e30f;
        #pragma unroll
        for (int m = 0; m < 8; ++m) {
            int k = (m >> 2) * 16 + g * 4 + (m & 3);
            vald[m] = ((bal >> k) & 1ull) != 0;
            if (vald[m]) m8 = fmaxf(m8, s[m]);
        }
        m8 = fmaxf(m8, __shfl_xor(m8, 16));
        m8 = fmaxf(m8, __shfl_xor(m8, 32));
        float es[8], ls = 0.f;
        #pragma unroll
        for (int m = 0; m < 8; ++m) {
            es[m] = vald[m] ? __expf(s[m] - m8) : 0.f;
            ls += es[m];
        }
        ls += __shfl_xor(ls, 16);
        ls += __shfl_xor(ls, 32);
        float inv = (ls > 0.f) ? 1.f / ls : 0.f;
        if (c == 0) {
            #pragma unroll
            for (int m = 0; m < 8; ++m) {
                int k = (m >> 2) * 16 + g * 4 + (m & 3);
                att_s[w][k] = es[m] * inv;
            }
        }

        // ---- out[n][l] = sum_k att[k] * e_u[k][l]  (f32) ----
        float acc = 0.f;
        #pragma unroll
        for (int k = 0; k < 32; ++k)
            acc += att_s[w][k] * eu[w][k][l];
        out[(size_t)n * 64 + l] = acc;
    }
}

extern "C" void kernel_launch(void* const* d_in, const int* in_sizes, int n_in,
                              void* d_out, int out_size, void* d_ws, size_t ws_size,
                              hipStream_t stream) {
    const float* u2e = (const float*)d_in[0];
    const float* W1  = (const float*)d_in[1];
    const float* b1  = (const float*)d_in[2];
    const float* W2  = (const float*)d_in[3];
    const float* b2  = (const float*)d_in[4];
    const float* W3  = (const float*)d_in[5];
    const float* b3  = (const float*)d_in[6];
    const int* nodes     = (const int*)d_in[7];
    const int* neigh_idx = (const int*)d_in[8];
    const void* mask     = d_in[9];

    const int N = in_sizes[7];           // number of nodes
    int* flag = (int*)d_ws;

    init_flag_kernel<<<1, 1, 0, stream>>>(flag);
    int nwords = in_sizes[9] / 4;        // safe to read under both layouts
    if (nwords > 100000) nwords = 100000;
    detect_mask_kernel<<<128, 256, 0, stream>>>((const unsigned*)mask, nwords, flag);

    graphrec_agg_kernel<<<1024, 256, 0, stream>>>(
        u2e, W1, b1, W2, b2, W3, b3, nodes, neigh_idx, mask, flag,
        (float*)d_out, N);
}